// Round 4
// baseline (148.279 us; speedup 1.0000x reference)
//
#include <hip/hip_runtime.h>
#include <hip/hip_bf16.h>

#define NB_MAX 8192
#define NTHR 256

__device__ __forceinline__ void get_grid(const float* __restrict__ cell,
                                         int& g0, int& g1, int& g2,
                                         float& d0, float& d1, float& d2) {
  d0 = cell[0]; d1 = cell[4]; d2 = cell[8];
  const float bl = (float)(5.2 + 1e-05);   // CUTOFF/BUCKETS + EXTRA_SPACE, f64 -> f32
  g0 = (int)floorf(d0 / bl) + 1;
  g1 = (int)floorf(d1 / bl) + 1;
  g2 = (int)floorf(d2 / bl) + 1;
}

__device__ __forceinline__ void atom_vec(const float* __restrict__ coord, int a,
                                         float d0, float d1, float d2,
                                         int g0, int g1, int g2,
                                         int& v0, int& v1, int& v2) {
  float x = coord[3 * a + 0], y = coord[3 * a + 1], z = coord[3 * a + 2];
  float fx = x / d0, fy = y / d1, fz = z / d2;
  v0 = (int)rintf(fx * (float)(g0 - 1));
  v1 = (int)rintf(fy * (float)(g1 - 1));
  v2 = (int)rintf(fz * (float)(g2 - 1));
}

// K1: frac out, bucket id per atom, histogram
__global__ void k_bucket_count(const float* __restrict__ coord,
                               const float* __restrict__ cell,
                               float* __restrict__ out_frac,
                               int* __restrict__ flat,
                               int* __restrict__ counts, int n) {
  int a = blockIdx.x * blockDim.x + threadIdx.x;
  if (a >= n) return;
  int g0, g1, g2; float d0, d1, d2;
  get_grid(cell, g0, g1, g2, d0, d1, d2);
  float x = coord[3 * a + 0], y = coord[3 * a + 1], z = coord[3 * a + 2];
  float fx = x / d0, fy = y / d1, fz = z / d2;
  out_frac[3 * a + 0] = fx;
  out_frac[3 * a + 1] = fy;
  out_frac[3 * a + 2] = fz;
  int v0 = (int)rintf(fx * (float)(g0 - 1));
  int v1 = (int)rintf(fy * (float)(g1 - 1));
  int v2 = (int)rintf(fz * (float)(g2 - 1));
  int b = v0 * (g1 * g2) + v1 * g1 + v2;   // reference scaling = (g1*g2, g1, 1)
  flat[a] = b;
  atomicAdd(&counts[b], 1);
}

// K2: scan over buckets (shuffle-scan, 2 barriers): cumcounts, pair offsets, total P
__global__ __launch_bounds__(1024) void k_scan_buckets(
    const float* __restrict__ cell,
    const int* __restrict__ counts,
    int* __restrict__ cumc,
    int* __restrict__ pairoff,
    int* __restrict__ scalars) {
  int g0, g1, g2; float d0, d1, d2;
  get_grid(cell, g0, g1, g2, d0, d1, d2);
  int nb = g0 * g1 * g2;
  const int T = 1024, IT = NB_MAX / 1024;
  __shared__ int wc[16], wp[16];
  int t = threadIdx.x;
  int lane = t & 63, wid = t >> 6;
  int base = t * IT;
  int cv[IT];
  int lc = 0, lp = 0;
  for (int i = 0; i < IT; ++i) {
    int idx = base + i;
    int c = (idx < nb) ? counts[idx] : 0;
    cv[i] = c;
    lc += c;
    lp += c * (c - 1) / 2;
  }
  // wave-inclusive scan of (lc, lp)
  int ic = lc, ip = lp;
  for (int off = 1; off < 64; off <<= 1) {
    int yc = __shfl_up(ic, off);
    int yp = __shfl_up(ip, off);
    if (lane >= off) { ic += yc; ip += yp; }
  }
  if (lane == 63) { wc[wid] = ic; wp[wid] = ip; }
  __syncthreads();
  if (wid == 0 && lane < 16) {
    int vc2 = wc[lane], vp2 = wp[lane];
    int sc2 = vc2, sp2 = vp2;
    for (int off = 1; off < 16; off <<= 1) {
      int yc = __shfl_up(sc2, off);
      int yp = __shfl_up(sp2, off);
      if (lane >= off) { sc2 += yc; sp2 += yp; }
    }
    wc[lane] = sc2 - vc2;  // exclusive wave offsets
    wp[lane] = sp2 - vp2;
  }
  __syncthreads();
  int ec = wc[wid] + (ic - lc);
  int ep = wp[wid] + (ip - lp);
  for (int i = 0; i < IT; ++i) {
    int idx = base + i;
    if (idx < nb) { cumc[idx] = ec; pairoff[idx] = ep; }
    ec += cv[i];
    ep += cv[i] * (cv[i] - 1) / 2;
  }
  if (t == T - 1) scalars[0] = ep;  // total P (within-image pair count)
}

// K3: scatter atoms into bucket segments (unordered within bucket)
__global__ void k_scatter(const int* __restrict__ flat,
                          const int* __restrict__ cumc,
                          int* __restrict__ fill,
                          int* __restrict__ sorted, int n) {
  int a = blockIdx.x * blockDim.x + threadIdx.x;
  if (a >= n) return;
  int b = flat[a];
  int pos = cumc[b] + atomicAdd(&fill[b], 1);
  sorted[pos] = a;
}

// K4: fused per-bucket wave kernel: rank-sort + perm outputs + within-image pairs.
// Block = 4 waves = 4 buckets.
__global__ void k_sort_perm_pairs(const float* __restrict__ cell,
                                  const int* __restrict__ counts,
                                  const int* __restrict__ cumc,
                                  const int* __restrict__ pairoff,
                                  const int* __restrict__ scalars,
                                  int* __restrict__ sorted,
                                  float* __restrict__ out_im,
                                  float* __restrict__ out_at,
                                  float* __restrict__ out) {
  int lane = threadIdx.x & 63;
  int b = blockIdx.x * 4 + (threadIdx.x >> 6);
  int g0, g1, g2; float d0, d1, d2;
  get_grid(cell, g0, g1, g2, d0, d1, d2);
  int nb = g0 * g1 * g2;
  if (b >= nb) return;
  int c = counts[b];
  if (c == 0) return;
  int s = cumc[b];
  if (c == 1) {
    if (lane == 0) {
      int a = sorted[s];
      out_im[s] = (float)a;
      out_at[a] = (float)s;
    }
    return;
  }
  if (c <= 64) {
    // rank sort (atom ids distinct -> unique ranks)
    int val = (lane < c) ? sorted[s + lane] : 0x7fffffff;
    int rank = 0;
    for (int j = 0; j < c; ++j) {
      int other = __shfl(val, j);
      rank += (other < val) ? 1 : 0;
    }
    if (lane < c) {
      sorted[s + rank] = val;
      out_im[s + rank] = (float)val;
      out_at[val] = (float)(s + rank);
    }
  } else if (lane == 0) {
    // serial fallback (never hit at these densities)
    for (int i = 1; i < c; ++i) {
      int key = sorted[s + i];
      int j = i - 1;
      while (j >= 0 && sorted[s + j] > key) {
        sorted[s + j + 1] = sorted[s + j];
        --j;
      }
      sorted[s + j + 1] = key;
    }
    for (int i = 0; i < c; ++i) {
      int a = sorted[s + i];
      out_im[s + i] = (float)a;
      out_at[a] = (float)(s + i);
    }
  }
  // within-image pairs: order k = l(l-1)/2 + u, l=1..c-1, u<l
  int off = pairoff[b];
  int P = scalars[0];
  int np = c * (c - 1) / 2;
  for (int k = lane; k < np; k += 64) {
    int l = (int)((1.0f + sqrtf(1.0f + 8.0f * (float)k)) * 0.5f);
    while (l * (l - 1) / 2 > k) --l;
    while ((l + 1) * l / 2 <= k) ++l;
    int u = k - l * (l - 1) / 2;
    out[off + k] = (float)(s + u);
    out[P + off + k] = (float)(s + l);
  }
}

// K5: per-atom neighbor-run length S(a) + block partial sums (fused)
__global__ void k_runlen(const float* __restrict__ coord,
                         const float* __restrict__ cell,
                         const int* __restrict__ counts,
                         int* __restrict__ Sarr,
                         int* __restrict__ blockpart, int n) {
  __shared__ int sm[NTHR];
  int t = threadIdx.x;
  int a = blockIdx.x * NTHR + t;
  int S = 0;
  if (a < n) {
    int g0, g1, g2; float d0, d1, d2;
    get_grid(cell, g0, g1, g2, d0, d1, d2);
    int v0, v1, v2;
    atom_vec(coord, a, d0, d1, d2, g0, g1, g2, v0, v1, v2);
    for (int m = 0; m < 7; ++m) {
      int dx = ((m >> 2) & 1) ? 0 : -1;
      int dy = ((m >> 1) & 1) ? 0 : -1;
      int dz = (m & 1) ? 0 : -1;
      int nx = v0 + dx; if (nx < 0) nx += g0;
      int ny = v1 + dy; if (ny < 0) ny += g1;
      int nz = v2 + dz; if (nz < 0) nz += g2;
      int nb_ = nx * (g1 * g2) + ny * g1 + nz;
      S += counts[nb_];
    }
    Sarr[a] = S;
  }
  sm[t] = S;
  __syncthreads();
  for (int off = NTHR / 2; off > 0; off >>= 1) {
    if (t < off) sm[t] += sm[t + off];
    __syncthreads();
  }
  if (t == 0) blockpart[blockIdx.x] = sm[0];
}

// K6: scan of block partials (shuffle-scan; up to 1024 blocks)
__global__ __launch_bounds__(1024) void k_scan_partials(
    const int* __restrict__ blockpart,
    int* __restrict__ blockoff,
    int* __restrict__ scalars, int nblocks) {
  __shared__ int ws[16];
  int t = threadIdx.x;
  int lane = t & 63, wid = t >> 6;
  int v = (t < nblocks) ? blockpart[t] : 0;
  int iv = v;
  for (int off = 1; off < 64; off <<= 1) {
    int y = __shfl_up(iv, off);
    if (lane >= off) iv += y;
  }
  if (lane == 63) ws[wid] = iv;
  __syncthreads();
  if (wid == 0 && lane < 16) {
    int v2 = ws[lane], s2 = v2;
    for (int off = 1; off < 16; off <<= 1) {
      int y = __shfl_up(s2, off);
      if (lane >= off) s2 += y;
    }
    ws[lane] = s2 - v2;
  }
  __syncthreads();
  int excl = ws[wid] + (iv - v);
  blockoff[t] = excl;
  if (t == 1023) scalars[1] = excl + v;  // total L (unused)
}

// K7: per-atom exclusive offsets Oarr[a] = prefix of S
__global__ void k_offsets(const int* __restrict__ Sarr,
                          const int* __restrict__ blockoff,
                          int* __restrict__ Oarr, int n) {
  __shared__ int ws[4];
  int t = threadIdx.x;
  int lane = t & 63, wid = t >> 6;
  int a = blockIdx.x * NTHR + t;
  int S = (a < n) ? Sarr[a] : 0;
  int iv = S;
  for (int off = 1; off < 64; off <<= 1) {
    int y = __shfl_up(iv, off);
    if (lane >= off) iv += y;
  }
  if (lane == 63) ws[wid] = iv;
  __syncthreads();
  if (wid == 0 && lane < 4) {
    int v2 = ws[lane], s2 = v2;
    for (int off = 1; off < 4; off <<= 1) {
      int y = __shfl_up(s2, off);
      if (lane >= off) s2 += y;
    }
    ws[lane] = s2 - v2;
  }
  __syncthreads();
  if (a < n) Oarr[a] = blockoff[blockIdx.x] + ws[wid] + (iv - S);
}

// K8: wave-per-atom emit of lower_between runs (coalesced stores)
__global__ void k_emit_wave(const float* __restrict__ coord,
                            const float* __restrict__ cell,
                            const int* __restrict__ counts,
                            const int* __restrict__ cumc,
                            const int* __restrict__ Oarr,
                            const int* __restrict__ scalars,
                            float* __restrict__ out, int n) {
  int a = (blockIdx.x * blockDim.x + threadIdx.x) >> 6;
  int lane = threadIdx.x & 63;
  if (a >= n) return;
  int g0, g1, g2; float d0, d1, d2;
  get_grid(cell, g0, g1, g2, d0, d1, d2);
  int v0, v1, v2;
  atom_vec(coord, a, d0, d1, d2, g0, g1, g2, v0, v1, v2);
  int segs[8];
  int cums[7];
  segs[0] = 0;
#pragma unroll
  for (int m = 0; m < 7; ++m) {
    int dx = ((m >> 2) & 1) ? 0 : -1;
    int dy = ((m >> 1) & 1) ? 0 : -1;
    int dz = (m & 1) ? 0 : -1;
    int nx = v0 + dx; if (nx < 0) nx += g0;
    int ny = v1 + dy; if (ny < 0) ny += g1;
    int nz = v2 + dz; if (nz < 0) nz += g2;
    int nb_ = nx * (g1 * g2) + ny * g1 + nz;
    cums[m] = cumc[nb_];
    segs[m + 1] = segs[m] + counts[nb_];
  }
  int S = segs[7];
  long base = 2L * (long)scalars[0] + (long)Oarr[a];
  for (int p = lane; p < S; p += 64) {
    int v = cums[0] + p;
#pragma unroll
    for (int m = 1; m < 7; ++m) {
      if (p >= segs[m]) v = cums[m] + (p - segs[m]);
    }
    out[base + p] = (float)v;
  }
}

extern "C" void kernel_launch(void* const* d_in, const int* in_sizes, int n_in,
                              void* d_out, int out_size, void* d_ws, size_t ws_size,
                              hipStream_t stream) {
  const float* coord = (const float*)d_in[0];
  const float* cell = (const float*)d_in[1];
  float* out = (float*)d_out;
  int n = in_sizes[0] / 3;

  int* W = (int*)d_ws;
  int* counts = W;                         // NB_MAX
  int* fill = W + NB_MAX;                  // NB_MAX
  int* scalars = W + 2 * NB_MAX;           // 16: [0]=P, [1]=L
  int* cumc = W + 2 * NB_MAX + 16;         // NB_MAX
  int* pairoff = cumc + NB_MAX;            // NB_MAX
  int* flat = pairoff + NB_MAX;            // n
  int* sorted = flat + n;                  // n
  int* Sarr = sorted + n;                  // n
  int* blockpart = Sarr + n;               // 1024
  int* blockoff = blockpart + 1024;        // 1024
  int* Oarr = blockoff + 1024;             // n

  // output chunk bases known on host: out = [2P | L | 3n | n | n]
  float* out_frac = out + (out_size - 5 * n);
  float* out_im = out + (out_size - 2 * n);
  float* out_at = out + (out_size - n);

  int nblocks = (n + NTHR - 1) / NTHR;

  // zero counts, fill, scalars (contiguous at ws start)
  hipMemsetAsync(d_ws, 0, (size_t)(2 * NB_MAX + 16) * sizeof(int), stream);

  k_bucket_count<<<nblocks, NTHR, 0, stream>>>(coord, cell, out_frac, flat, counts, n);
  k_scan_buckets<<<1, 1024, 0, stream>>>(cell, counts, cumc, pairoff, scalars);
  k_scatter<<<nblocks, NTHR, 0, stream>>>(flat, cumc, fill, sorted, n);
  k_sort_perm_pairs<<<NB_MAX / 4, 256, 0, stream>>>(cell, counts, cumc, pairoff, scalars,
                                                    sorted, out_im, out_at, out);
  k_runlen<<<nblocks, NTHR, 0, stream>>>(coord, cell, counts, Sarr, blockpart, n);
  k_scan_partials<<<1, 1024, 0, stream>>>(blockpart, blockoff, scalars, nblocks);
  k_offsets<<<nblocks, NTHR, 0, stream>>>(Sarr, blockoff, Oarr, n);
  k_emit_wave<<<(n + 3) / 4, 256, 0, stream>>>(coord, cell, counts, cumc, Oarr, scalars, out, n);
}

// Round 5
// 132.466 us; speedup vs baseline: 1.1194x; 1.1194x over previous
//
#include <hip/hip_runtime.h>
#include <hip/hip_bf16.h>

#define NB_MAX 8192
#define NTHR 256

__device__ __forceinline__ void get_grid(const float* __restrict__ cell,
                                         int& g0, int& g1, int& g2,
                                         float& d0, float& d1, float& d2) {
  d0 = cell[0]; d1 = cell[4]; d2 = cell[8];
  const float bl = (float)(5.2 + 1e-05);   // CUTOFF/BUCKETS + EXTRA_SPACE, f64 -> f32
  g0 = (int)floorf(d0 / bl) + 1;
  g1 = (int)floorf(d1 / bl) + 1;
  g2 = (int)floorf(d2 / bl) + 1;
}

// K1: frac out, bucket id + packed vec per atom, histogram; thread 0 publishes grid dims
__global__ void k_bucket_count(const float* __restrict__ coord,
                               const float* __restrict__ cell,
                               float* __restrict__ out_frac,
                               int* __restrict__ flat,
                               int* __restrict__ pv,
                               int* __restrict__ counts,
                               int* __restrict__ scalars, int n) {
  int a = blockIdx.x * blockDim.x + threadIdx.x;
  if (a >= n) return;
  int g0, g1, g2; float d0, d1, d2;
  get_grid(cell, g0, g1, g2, d0, d1, d2);
  if (a == 0) {
    scalars[8] = g0; scalars[9] = g1; scalars[10] = g2;
    scalars[11] = g1 * g2; scalars[12] = g0 * g1 * g2;
  }
  float x = coord[3 * a + 0], y = coord[3 * a + 1], z = coord[3 * a + 2];
  float fx = x / d0, fy = y / d1, fz = z / d2;
  out_frac[3 * a + 0] = fx;
  out_frac[3 * a + 1] = fy;
  out_frac[3 * a + 2] = fz;
  int v0 = (int)rintf(fx * (float)(g0 - 1));
  int v1 = (int)rintf(fy * (float)(g1 - 1));
  int v2 = (int)rintf(fz * (float)(g2 - 1));
  int b = v0 * (g1 * g2) + v1 * g1 + v2;   // reference scaling = (g1*g2, g1, 1)
  flat[a] = b;
  pv[a] = (v0 << 20) | (v1 << 10) | v2;
  atomicAdd(&counts[b], 1);
}

// K2: scan over buckets (shuffle-scan, 2 barriers): cumcounts, pair offsets, total P
__global__ __launch_bounds__(1024) void k_scan_buckets(
    const int* __restrict__ counts,
    int* __restrict__ cumc,
    int* __restrict__ pairoff,
    int* __restrict__ scalars) {
  int nb = scalars[12];
  const int T = 1024, IT = NB_MAX / 1024;
  __shared__ int wc[16], wp[16];
  int t = threadIdx.x;
  int lane = t & 63, wid = t >> 6;
  int base = t * IT;
  int cv[IT];
  int lc = 0, lp = 0;
  for (int i = 0; i < IT; ++i) {
    int idx = base + i;
    int c = (idx < nb) ? counts[idx] : 0;
    cv[i] = c;
    lc += c;
    lp += c * (c - 1) / 2;
  }
  int ic = lc, ip = lp;
  for (int off = 1; off < 64; off <<= 1) {
    int yc = __shfl_up(ic, off);
    int yp = __shfl_up(ip, off);
    if (lane >= off) { ic += yc; ip += yp; }
  }
  if (lane == 63) { wc[wid] = ic; wp[wid] = ip; }
  __syncthreads();
  if (wid == 0 && lane < 16) {
    int vc2 = wc[lane], vp2 = wp[lane];
    int sc2 = vc2, sp2 = vp2;
    for (int off = 1; off < 16; off <<= 1) {
      int yc = __shfl_up(sc2, off);
      int yp = __shfl_up(sp2, off);
      if (lane >= off) { sc2 += yc; sp2 += yp; }
    }
    wc[lane] = sc2 - vc2;  // exclusive wave offsets
    wp[lane] = sp2 - vp2;
  }
  __syncthreads();
  int ec = wc[wid] + (ic - lc);
  int ep = wp[wid] + (ip - lp);
  for (int i = 0; i < IT; ++i) {
    int idx = base + i;
    if (idx < nb) { cumc[idx] = ec; pairoff[idx] = ep; }
    ec += cv[i];
    ep += cv[i] * (cv[i] - 1) / 2;
  }
  if (t == T - 1) scalars[0] = ep;  // total P
}

// K3: scatter into bucket segments + per-atom run length S + block partials (fused)
__global__ void k_scatter_runlen(const int* __restrict__ flat,
                                 const int* __restrict__ pv,
                                 const int* __restrict__ cumc,
                                 const int* __restrict__ counts,
                                 const int* __restrict__ scalars,
                                 int* __restrict__ fill,
                                 int* __restrict__ sorted,
                                 int* __restrict__ Sarr,
                                 int* __restrict__ blockpart, int n) {
  __shared__ int sm[NTHR];
  int t = threadIdx.x;
  int a = blockIdx.x * NTHR + t;
  int S = 0;
  if (a < n) {
    int b = flat[a];
    int pos = cumc[b] + atomicAdd(&fill[b], 1);
    sorted[pos] = a;
    int g0 = scalars[8], g1 = scalars[9], g2 = scalars[10], g12 = scalars[11];
    int p = pv[a];
    int v0 = p >> 20, v1 = (p >> 10) & 1023, v2 = p & 1023;
#pragma unroll
    for (int m = 0; m < 7; ++m) {
      int dx = ((m >> 2) & 1) ? 0 : -1;
      int dy = ((m >> 1) & 1) ? 0 : -1;
      int dz = (m & 1) ? 0 : -1;
      int nx = v0 + dx; if (nx < 0) nx += g0;
      int ny = v1 + dy; if (ny < 0) ny += g1;
      int nz = v2 + dz; if (nz < 0) nz += g2;
      S += counts[nx * g12 + ny * g1 + nz];
    }
    Sarr[a] = S;
  }
  sm[t] = S;
  __syncthreads();
  for (int off = NTHR / 2; off > 0; off >>= 1) {
    if (t < off) sm[t] += sm[t + off];
    __syncthreads();
  }
  if (t == 0) blockpart[blockIdx.x] = sm[0];
}

// K4: fused per-bucket wave kernel: rank-sort + perm outputs + within-image pairs.
__global__ void k_sort_perm_pairs(const int* __restrict__ counts,
                                  const int* __restrict__ cumc,
                                  const int* __restrict__ pairoff,
                                  const int* __restrict__ scalars,
                                  int* __restrict__ sorted,
                                  float* __restrict__ out_im,
                                  float* __restrict__ out_at,
                                  float* __restrict__ out) {
  int lane = threadIdx.x & 63;
  int b = blockIdx.x * 4 + (threadIdx.x >> 6);
  int nb = scalars[12];
  if (b >= nb) return;
  int c = counts[b];
  if (c == 0) return;
  int s = cumc[b];
  if (c == 1) {
    if (lane == 0) {
      int a = sorted[s];
      out_im[s] = (float)a;
      out_at[a] = (float)s;
    }
    return;
  }
  if (c <= 64) {
    int val = (lane < c) ? sorted[s + lane] : 0x7fffffff;
    int rank = 0;
    for (int j = 0; j < c; ++j) {
      int other = __shfl(val, j);
      rank += (other < val) ? 1 : 0;
    }
    if (lane < c) {
      sorted[s + rank] = val;
      out_im[s + rank] = (float)val;
      out_at[val] = (float)(s + rank);
    }
  } else if (lane == 0) {
    for (int i = 1; i < c; ++i) {
      int key = sorted[s + i];
      int j = i - 1;
      while (j >= 0 && sorted[s + j] > key) {
        sorted[s + j + 1] = sorted[s + j];
        --j;
      }
      sorted[s + j + 1] = key;
    }
    for (int i = 0; i < c; ++i) {
      int a = sorted[s + i];
      out_im[s + i] = (float)a;
      out_at[a] = (float)(s + i);
    }
  }
  int off = pairoff[b];
  int P = scalars[0];
  int np = c * (c - 1) / 2;
  for (int k = lane; k < np; k += 64) {
    int l = (int)((1.0f + sqrtf(1.0f + 8.0f * (float)k)) * 0.5f);
    while (l * (l - 1) / 2 > k) --l;
    while ((l + 1) * l / 2 <= k) ++l;
    int u = k - l * (l - 1) / 2;
    out[off + k] = (float)(s + u);
    out[P + off + k] = (float)(s + l);
  }
}

// K5: scan of block partials (shuffle-scan; up to 1024 blocks)
__global__ __launch_bounds__(1024) void k_scan_partials(
    const int* __restrict__ blockpart,
    int* __restrict__ blockoff,
    int* __restrict__ scalars, int nblocks) {
  __shared__ int ws[16];
  int t = threadIdx.x;
  int lane = t & 63, wid = t >> 6;
  int v = (t < nblocks) ? blockpart[t] : 0;
  int iv = v;
  for (int off = 1; off < 64; off <<= 1) {
    int y = __shfl_up(iv, off);
    if (lane >= off) iv += y;
  }
  if (lane == 63) ws[wid] = iv;
  __syncthreads();
  if (wid == 0 && lane < 16) {
    int v2 = ws[lane], s2 = v2;
    for (int off = 1; off < 16; off <<= 1) {
      int y = __shfl_up(s2, off);
      if (lane >= off) s2 += y;
    }
    ws[lane] = s2 - v2;
  }
  __syncthreads();
  int excl = ws[wid] + (iv - v);
  blockoff[t] = excl;
  if (t == 1023) scalars[1] = excl + v;
}

// K6: thread-per-atom emit of lower_between runs (block scan prologue for offsets)
__global__ void k_emit(const int* __restrict__ pv,
                       const int* __restrict__ counts,
                       const int* __restrict__ cumc,
                       const int* __restrict__ Sarr,
                       const int* __restrict__ blockoff,
                       const int* __restrict__ scalars,
                       float* __restrict__ out, int n) {
  __shared__ int ws[4];
  int t = threadIdx.x;
  int lane = t & 63, wid = t >> 6;
  int a = blockIdx.x * NTHR + t;
  int S = (a < n) ? Sarr[a] : 0;
  int iv = S;
  for (int off = 1; off < 64; off <<= 1) {
    int y = __shfl_up(iv, off);
    if (lane >= off) iv += y;
  }
  if (lane == 63) ws[wid] = iv;
  __syncthreads();
  if (wid == 0 && lane < 4) {
    int v2 = ws[lane], s2 = v2;
    for (int off = 1; off < 4; off <<= 1) {
      int y = __shfl_up(s2, off);
      if (lane >= off) s2 += y;
    }
    ws[lane] = s2 - v2;
  }
  __syncthreads();
  if (a >= n) return;
  int excl = ws[wid] + (iv - S);
  int g0 = scalars[8], g1 = scalars[9], g2 = scalars[10], g12 = scalars[11];
  int p = pv[a];
  int v0 = p >> 20, v1 = (p >> 10) & 1023, v2 = p & 1023;
  long base = 2L * (long)scalars[0] + (long)blockoff[blockIdx.x] + (long)excl;
  int k = 0;
#pragma unroll
  for (int m = 0; m < 7; ++m) {
    int dx = ((m >> 2) & 1) ? 0 : -1;
    int dy = ((m >> 1) & 1) ? 0 : -1;
    int dz = (m & 1) ? 0 : -1;
    int nx = v0 + dx; if (nx < 0) nx += g0;
    int ny = v1 + dy; if (ny < 0) ny += g1;
    int nz = v2 + dz; if (nz < 0) nz += g2;
    int nb_ = nx * g12 + ny * g1 + nz;
    int c = counts[nb_];
    int cum = cumc[nb_];
    for (int j = 0; j < c; ++j) {
      out[base + k] = (float)(cum + j);
      ++k;
    }
  }
}

extern "C" void kernel_launch(void* const* d_in, const int* in_sizes, int n_in,
                              void* d_out, int out_size, void* d_ws, size_t ws_size,
                              hipStream_t stream) {
  const float* coord = (const float*)d_in[0];
  const float* cell = (const float*)d_in[1];
  float* out = (float*)d_out;
  int n = in_sizes[0] / 3;

  int* W = (int*)d_ws;
  int* counts = W;                         // NB_MAX
  int* fill = W + NB_MAX;                  // NB_MAX
  int* scalars = W + 2 * NB_MAX;           // 16: [0]=P [1]=L [8..12]=g0,g1,g2,g1*g2,nb
  int* cumc = W + 2 * NB_MAX + 16;         // NB_MAX
  int* pairoff = cumc + NB_MAX;            // NB_MAX
  int* flat = pairoff + NB_MAX;            // n
  int* pv = flat + n;                      // n
  int* sorted = pv + n;                    // n
  int* Sarr = sorted + n;                  // n
  int* blockpart = Sarr + n;               // 1024
  int* blockoff = blockpart + 1024;        // 1024

  // output chunk bases known on host: out = [2P | L | 3n | n | n]
  float* out_frac = out + (out_size - 5 * n);
  float* out_im = out + (out_size - 2 * n);
  float* out_at = out + (out_size - n);

  int nblocks = (n + NTHR - 1) / NTHR;

  hipMemsetAsync(d_ws, 0, (size_t)(2 * NB_MAX + 16) * sizeof(int), stream);

  k_bucket_count<<<nblocks, NTHR, 0, stream>>>(coord, cell, out_frac, flat, pv, counts, scalars, n);
  k_scan_buckets<<<1, 1024, 0, stream>>>(counts, cumc, pairoff, scalars);
  k_scatter_runlen<<<nblocks, NTHR, 0, stream>>>(flat, pv, cumc, counts, scalars,
                                                 fill, sorted, Sarr, blockpart, n);
  k_sort_perm_pairs<<<NB_MAX / 4, 256, 0, stream>>>(counts, cumc, pairoff, scalars,
                                                    sorted, out_im, out_at, out);
  k_scan_partials<<<1, 1024, 0, stream>>>(blockpart, blockoff, scalars, nblocks);
  k_emit<<<nblocks, NTHR, 0, stream>>>(pv, counts, cumc, Sarr, blockoff, scalars, out, n);
}

// Round 6
// 115.655 us; speedup vs baseline: 1.2821x; 1.1454x over previous
//
#include <hip/hip_runtime.h>
#include <hip/hip_bf16.h>

#define NB_MAX 8192
#define NTHR 256

__device__ __forceinline__ void get_grid(const float* __restrict__ cell,
                                         int& g0, int& g1, int& g2,
                                         float& d0, float& d1, float& d2) {
  d0 = cell[0]; d1 = cell[4]; d2 = cell[8];
  const float bl = (float)(5.2 + 1e-05);   // CUTOFF/BUCKETS + EXTRA_SPACE, f64 -> f32
  g0 = (int)floorf(d0 / bl) + 1;
  g1 = (int)floorf(d1 / bl) + 1;
  g2 = (int)floorf(d2 / bl) + 1;
}

// K1: frac out, bucket id + packed vec per atom, histogram; thread 0 publishes grid dims
__global__ void k_bucket_count(const float* __restrict__ coord,
                               const float* __restrict__ cell,
                               float* __restrict__ out_frac,
                               int* __restrict__ flat,
                               int* __restrict__ pv,
                               int* __restrict__ counts,
                               int* __restrict__ scalars, int n) {
  int a = blockIdx.x * blockDim.x + threadIdx.x;
  if (a >= n) return;
  int g0, g1, g2; float d0, d1, d2;
  get_grid(cell, g0, g1, g2, d0, d1, d2);
  if (a == 0) {
    scalars[8] = g0; scalars[9] = g1; scalars[10] = g2;
    scalars[11] = g1 * g2; scalars[12] = g0 * g1 * g2;
  }
  float x = coord[3 * a + 0], y = coord[3 * a + 1], z = coord[3 * a + 2];
  float fx = x / d0, fy = y / d1, fz = z / d2;
  out_frac[3 * a + 0] = fx;
  out_frac[3 * a + 1] = fy;
  out_frac[3 * a + 2] = fz;
  int v0 = (int)rintf(fx * (float)(g0 - 1));
  int v1 = (int)rintf(fy * (float)(g1 - 1));
  int v2 = (int)rintf(fz * (float)(g2 - 1));
  int b = v0 * (g1 * g2) + v1 * g1 + v2;   // reference scaling = (g1*g2, g1, 1)
  flat[a] = b;
  pv[a] = (v0 << 20) | (v1 << 10) | v2;
  atomicAdd(&counts[b], 1);
}

// K2: scan over buckets (shuffle-scan, 2 barriers): cumcounts, pair offsets, total P
__global__ __launch_bounds__(1024) void k_scan_buckets(
    const int* __restrict__ counts,
    int* __restrict__ cumc,
    int* __restrict__ pairoff,
    int* __restrict__ scalars) {
  int nb = scalars[12];
  const int T = 1024, IT = NB_MAX / 1024;
  __shared__ int wc[16], wp[16];
  int t = threadIdx.x;
  int lane = t & 63, wid = t >> 6;
  int base = t * IT;
  int cv[IT];
  int lc = 0, lp = 0;
  for (int i = 0; i < IT; ++i) {
    int idx = base + i;
    int c = (idx < nb) ? counts[idx] : 0;
    cv[i] = c;
    lc += c;
    lp += c * (c - 1) / 2;
  }
  int ic = lc, ip = lp;
  for (int off = 1; off < 64; off <<= 1) {
    int yc = __shfl_up(ic, off);
    int yp = __shfl_up(ip, off);
    if (lane >= off) { ic += yc; ip += yp; }
  }
  if (lane == 63) { wc[wid] = ic; wp[wid] = ip; }
  __syncthreads();
  if (wid == 0 && lane < 16) {
    int vc2 = wc[lane], vp2 = wp[lane];
    int sc2 = vc2, sp2 = vp2;
    for (int off = 1; off < 16; off <<= 1) {
      int yc = __shfl_up(sc2, off);
      int yp = __shfl_up(sp2, off);
      if (lane >= off) { sc2 += yc; sp2 += yp; }
    }
    wc[lane] = sc2 - vc2;  // exclusive wave offsets
    wp[lane] = sp2 - vp2;
  }
  __syncthreads();
  int ec = wc[wid] + (ic - lc);
  int ep = wp[wid] + (ip - lp);
  for (int i = 0; i < IT; ++i) {
    int idx = base + i;
    if (idx < nb) { cumc[idx] = ec; pairoff[idx] = ep; }
    ec += cv[i];
    ep += cv[i] * (cv[i] - 1) / 2;
  }
  if (t == T - 1) scalars[0] = ep;  // total P
}

// K3: scatter into bucket segments + run length S + block-local exclusive offsets
//     Oarr[a] (within this 256-atom block) + blockpart totals
__global__ void k_scatter_runlen(const int* __restrict__ flat,
                                 const int* __restrict__ pv,
                                 const int* __restrict__ cumc,
                                 const int* __restrict__ counts,
                                 const int* __restrict__ scalars,
                                 int* __restrict__ fill,
                                 int* __restrict__ sorted,
                                 int* __restrict__ Oarr,
                                 int* __restrict__ blockpart, int n) {
  __shared__ int ws[4];
  int t = threadIdx.x;
  int lane = t & 63, wid = t >> 6;
  int a = blockIdx.x * NTHR + t;
  int S = 0;
  if (a < n) {
    int b = flat[a];
    int pos = cumc[b] + atomicAdd(&fill[b], 1);
    sorted[pos] = a;
    int g0 = scalars[8], g1 = scalars[9], g2 = scalars[10], g12 = scalars[11];
    int p = pv[a];
    int v0 = p >> 20, v1 = (p >> 10) & 1023, v2 = p & 1023;
#pragma unroll
    for (int m = 0; m < 7; ++m) {
      int dx = ((m >> 2) & 1) ? 0 : -1;
      int dy = ((m >> 1) & 1) ? 0 : -1;
      int dz = (m & 1) ? 0 : -1;
      int nx = v0 + dx; if (nx < 0) nx += g0;
      int ny = v1 + dy; if (ny < 0) ny += g1;
      int nz = v2 + dz; if (nz < 0) nz += g2;
      S += counts[nx * g12 + ny * g1 + nz];
    }
  }
  // wave-inclusive scan of S
  int iv = S;
  for (int off = 1; off < 64; off <<= 1) {
    int y = __shfl_up(iv, off);
    if (lane >= off) iv += y;
  }
  if (lane == 63) ws[wid] = iv;
  __syncthreads();
  if (wid == 0 && lane < 4) {
    int v2 = ws[lane], s2 = v2;
    for (int off = 1; off < 4; off <<= 1) {
      int y = __shfl_up(s2, off);
      if (lane >= off) s2 += y;
    }
    ws[lane] = s2 - v2;           // exclusive wave offsets
    if (lane == 3) blockpart[blockIdx.x] = s2;  // block total
  }
  __syncthreads();
  if (a < n) Oarr[a] = ws[wid] + (iv - S);
}

// K4: per-bucket wave kernel: rank-sort + perm outputs + within-image pairs.
//     Last block instead scans blockpart -> blockoff (exclusive).
__global__ void k_sort_perm_pairs(const int* __restrict__ counts,
                                  const int* __restrict__ cumc,
                                  const int* __restrict__ pairoff,
                                  const int* __restrict__ scalars,
                                  int* __restrict__ sorted,
                                  float* __restrict__ out_im,
                                  float* __restrict__ out_at,
                                  float* __restrict__ out,
                                  const int* __restrict__ blockpart,
                                  int* __restrict__ blockoff, int nblocks) {
  __shared__ int shm[4];
  int t = threadIdx.x;
  int lane = t & 63, wid = t >> 6;
  if (blockIdx.x == gridDim.x - 1) {
    // exclusive scan of blockpart[0..nblocks) into blockoff (1024 slots, IT=4)
    int base = t * 4;
    int cv[4];
    int ls = 0;
    for (int i = 0; i < 4; ++i) {
      int v = (base + i < nblocks) ? blockpart[base + i] : 0;
      cv[i] = v;
      ls += v;
    }
    int il = ls;
    for (int off = 1; off < 64; off <<= 1) {
      int y = __shfl_up(il, off);
      if (lane >= off) il += y;
    }
    if (lane == 63) shm[wid] = il;
    __syncthreads();
    if (wid == 0 && lane < 4) {
      int v2 = shm[lane], s2 = v2;
      for (int off = 1; off < 4; off <<= 1) {
        int y = __shfl_up(s2, off);
        if (lane >= off) s2 += y;
      }
      shm[lane] = s2 - v2;
    }
    __syncthreads();
    int e = shm[wid] + (il - ls);
    for (int i = 0; i < 4; ++i) {
      blockoff[base + i] = e;
      e += cv[i];
    }
    return;
  }
  int b = blockIdx.x * 4 + wid;
  int nb = scalars[12];
  if (b >= nb) return;
  int c = counts[b];
  if (c == 0) return;
  int s = cumc[b];
  if (c == 1) {
    if (lane == 0) {
      int a = sorted[s];
      out_im[s] = (float)a;
      out_at[a] = (float)s;
    }
    return;
  }
  if (c <= 64) {
    int val = (lane < c) ? sorted[s + lane] : 0x7fffffff;
    int rank = 0;
    for (int j = 0; j < c; ++j) {
      int other = __shfl(val, j);
      rank += (other < val) ? 1 : 0;
    }
    if (lane < c) {
      sorted[s + rank] = val;
      out_im[s + rank] = (float)val;
      out_at[val] = (float)(s + rank);
    }
  } else if (lane == 0) {
    for (int i = 1; i < c; ++i) {
      int key = sorted[s + i];
      int j = i - 1;
      while (j >= 0 && sorted[s + j] > key) {
        sorted[s + j + 1] = sorted[s + j];
        --j;
      }
      sorted[s + j + 1] = key;
    }
    for (int i = 0; i < c; ++i) {
      int a = sorted[s + i];
      out_im[s + i] = (float)a;
      out_at[a] = (float)(s + i);
    }
  }
  int off = pairoff[b];
  int P = scalars[0];
  int np = c * (c - 1) / 2;
  for (int k = lane; k < np; k += 64) {
    int l = (int)((1.0f + sqrtf(1.0f + 8.0f * (float)k)) * 0.5f);
    while (l * (l - 1) / 2 > k) --l;
    while ((l + 1) * l / 2 <= k) ++l;
    int u = k - l * (l - 1) / 2;
    out[off + k] = (float)(s + u);
    out[P + off + k] = (float)(s + l);
  }
}

// K5: 16-lane-group emit of lower_between runs (coalesced 64B stores per atom)
__global__ void k_emit16(const int* __restrict__ pv,
                         const int* __restrict__ counts,
                         const int* __restrict__ cumc,
                         const int* __restrict__ Oarr,
                         const int* __restrict__ blockoff,
                         const int* __restrict__ scalars,
                         float* __restrict__ out, int n) {
  int gt = blockIdx.x * blockDim.x + threadIdx.x;
  int a = gt >> 4;
  int l16 = gt & 15;
  if (a >= n) return;
  int g0 = scalars[8], g1 = scalars[9], g2 = scalars[10], g12 = scalars[11];
  int p = pv[a];
  int v0 = p >> 20, v1 = (p >> 10) & 1023, v2 = p & 1023;
  int segs[8];
  int cums[7];
  segs[0] = 0;
#pragma unroll
  for (int m = 0; m < 7; ++m) {
    int dx = ((m >> 2) & 1) ? 0 : -1;
    int dy = ((m >> 1) & 1) ? 0 : -1;
    int dz = (m & 1) ? 0 : -1;
    int nx = v0 + dx; if (nx < 0) nx += g0;
    int ny = v1 + dy; if (ny < 0) ny += g1;
    int nz = v2 + dz; if (nz < 0) nz += g2;
    int nb_ = nx * g12 + ny * g1 + nz;
    cums[m] = cumc[nb_];
    segs[m + 1] = segs[m] + counts[nb_];
  }
  int S = segs[7];
  long base = 2L * (long)scalars[0] + (long)blockoff[a >> 8] + (long)Oarr[a];
  for (int q = l16; q < S; q += 16) {
    int v = cums[0] + q;
#pragma unroll
    for (int m = 1; m < 7; ++m) {
      if (q >= segs[m]) v = cums[m] + (q - segs[m]);
    }
    out[base + q] = (float)v;
  }
}

extern "C" void kernel_launch(void* const* d_in, const int* in_sizes, int n_in,
                              void* d_out, int out_size, void* d_ws, size_t ws_size,
                              hipStream_t stream) {
  const float* coord = (const float*)d_in[0];
  const float* cell = (const float*)d_in[1];
  float* out = (float*)d_out;
  int n = in_sizes[0] / 3;

  int* W = (int*)d_ws;
  int* counts = W;                         // NB_MAX
  int* fill = W + NB_MAX;                  // NB_MAX
  int* scalars = W + 2 * NB_MAX;           // 16: [0]=P [8..12]=g0,g1,g2,g1*g2,nb
  int* cumc = W + 2 * NB_MAX + 16;         // NB_MAX
  int* pairoff = cumc + NB_MAX;            // NB_MAX
  int* flat = pairoff + NB_MAX;            // n
  int* pv = flat + n;                      // n
  int* sorted = pv + n;                    // n
  int* Oarr = sorted + n;                  // n (block-local exclusive offsets)
  int* blockpart = Oarr + n;               // 1024
  int* blockoff = blockpart + 1024;        // 1024

  // output chunk bases known on host: out = [2P | L | 3n | n | n]
  float* out_frac = out + (out_size - 5 * n);
  float* out_im = out + (out_size - 2 * n);
  float* out_at = out + (out_size - n);

  int nblocks = (n + NTHR - 1) / NTHR;

  hipMemsetAsync(d_ws, 0, (size_t)(2 * NB_MAX + 16) * sizeof(int), stream);

  k_bucket_count<<<nblocks, NTHR, 0, stream>>>(coord, cell, out_frac, flat, pv, counts, scalars, n);
  k_scan_buckets<<<1, 1024, 0, stream>>>(counts, cumc, pairoff, scalars);
  k_scatter_runlen<<<nblocks, NTHR, 0, stream>>>(flat, pv, cumc, counts, scalars,
                                                 fill, sorted, Oarr, blockpart, n);
  k_sort_perm_pairs<<<NB_MAX / 4 + 1, 256, 0, stream>>>(counts, cumc, pairoff, scalars,
                                                        sorted, out_im, out_at, out,
                                                        blockpart, blockoff, nblocks);
  k_emit16<<<(n * 16 + 255) / 256, 256, 0, stream>>>(pv, counts, cumc, Oarr, blockoff,
                                                     scalars, out, n);
}